// Round 2
// baseline (386.419 us; speedup 1.0000x reference)
//
#include <hip/hip_runtime.h>

#define TPB 256

// ---------------------------------------------------------------------------
// Kernel A: block-partitioned fused kernel.
//   blocks [0, n_gemv_blocks):     GEMV partial sums (read-bound)
//   blocks [n_gemv_blocks, ...):   base-pattern fill of both IBF tensors
//                                  (write-bound; row 0 gets base value only,
//                                  finisher overwrites it with coeff product)
// Overlapping the two phases lets reads and writes share HBM concurrently.
// ---------------------------------------------------------------------------
__global__ __launch_bounds__(TPB) void fused_gemv_fill(
    const float* __restrict__ U, const float* __restrict__ O,
    const float* __restrict__ pos, const float* __restrict__ neg,
    const float* __restrict__ intervals,
    float* __restrict__ pu, float* __restrict__ po,   // (nchunks, ncols) partials
    float* __restrict__ outU, float* __restrict__ outO,
    int K, int ncols,
    int col_tiles, int rpc,
    int shift, int mask, int n4total, int n_gemv_blocks) {
  int b = blockIdx.x;

  if (b < n_gemv_blocks) {
    // ---- GEMV partial: su[j] = sum pos*U + neg*O ; so[j] = sum pos*O + neg*U
    int tile  = b % col_tiles;
    int chunk = b / col_tiles;
    int j = tile * TPB + threadIdx.x;
    if (j >= ncols) return;
    int k0 = chunk * rpc;
    int k1 = k0 + rpc; if (k1 > K) k1 = K;

    const float* Uq = U + (size_t)k0 * ncols + j;
    const float* Oq = O + (size_t)k0 * ncols + j;
    const size_t st = (size_t)ncols;
    float au = 0.f, ao = 0.f;
    int k = k0;
    for (; k + 4 <= k1; k += 4) {
      float p0 = pos[k],   p1 = pos[k+1], p2 = pos[k+2], p3 = pos[k+3];
      float n0 = neg[k],   n1 = neg[k+1], n2 = neg[k+2], n3 = neg[k+3];
      float a0 = Uq[0], a1 = Uq[st], a2 = Uq[2*st], a3 = Uq[3*st];
      float b0 = Oq[0], b1 = Oq[st], b2 = Oq[2*st], b3 = Oq[3*st];
      Uq += 4*st; Oq += 4*st;
      au = fmaf(p0, a0, au); au = fmaf(n0, b0, au);
      ao = fmaf(p0, b0, ao); ao = fmaf(n0, a0, ao);
      au = fmaf(p1, a1, au); au = fmaf(n1, b1, au);
      ao = fmaf(p1, b1, ao); ao = fmaf(n1, a1, ao);
      au = fmaf(p2, a2, au); au = fmaf(n2, b2, au);
      ao = fmaf(p2, b2, ao); ao = fmaf(n2, a2, ao);
      au = fmaf(p3, a3, au); au = fmaf(n3, b3, au);
      ao = fmaf(p3, b3, ao); ao = fmaf(n3, a3, ao);
    }
    for (; k < k1; ++k) {
      float p = pos[k], n = neg[k];
      float a = Uq[0], bb = Oq[0];
      Uq += st; Oq += st;
      au = fmaf(p, a, au); au = fmaf(n, bb, au);
      ao = fmaf(p, bb, ao); ao = fmaf(n, a, ao);
    }
    pu[(size_t)chunk * ncols + j] = au;
    po[(size_t)chunk * ncols + j] = ao;
    return;
  }

  // ---- Fill: base pattern, one float4 (rows r0, r0+1 of one block) per thread
  int i4 = (b - n_gemv_blocks) * TPB + threadIdx.x;
  if (i4 >= n4total) return;
  int i = i4 << 2;                 // element index within one tensor
  int blk = i >> shift;            // block index in [0, n_vars]
  int within = i & mask;
  int r0 = within >> 1;            // even row; float4 = rows r0, r0+1

  float4 v = make_float4(1.f, 1.f, 1.f, 1.f);
  if (r0 == blk) {                 // diag at even row
    v.x = intervals[2 * blk];
    v.y = intervals[2 * blk + 1];
  } else if (r0 + 1 == blk) {      // diag at odd row
    v.z = intervals[2 * blk];
    v.w = intervals[2 * blk + 1];
  }
  reinterpret_cast<float4*>(outU)[i4] = v;
  reinterpret_cast<float4*>(outO)[i4] = v;
}

// ---------------------------------------------------------------------------
// Scalar fill fallback (non-pow2 n_vars): base pattern only.
// ---------------------------------------------------------------------------
__global__ __launch_bounds__(TPB) void fill_scalar(
    const float* __restrict__ intervals,
    float* __restrict__ outU, float* __restrict__ outO,
    int n_vars, long long S) {
  long long tid = (long long)blockIdx.x * blockDim.x + threadIdx.x;
  long long nthreads = (long long)gridDim.x * blockDim.x;
  int two_n = 2 * n_vars;
  for (long long i = tid; i < S; i += nthreads) {
    int blk = (int)(i / two_n);
    int within = (int)(i - (long long)blk * two_n);
    int r = within >> 1;
    int c = within & 1;
    float v = 1.f;
    if (r == blk) v = intervals[2 * r + c];
    outU[i] = v;
    outO[i] = v;
  }
}

// ---------------------------------------------------------------------------
// Kernel B (finisher): reduce partials, write row-0 elements + degree vectors.
//   t in [0, ncols):        under coeff j=t
//   t in [ncols, 2*ncols):  over  coeff j=t-ncols
// Row 0 of block j, cols 0..1: (j==0 ? intervals[0][c] : 1) * (sum + bias)
// ---------------------------------------------------------------------------
__global__ __launch_bounds__(TPB) void finish(
    const float* __restrict__ pu, const float* __restrict__ po,
    const float* __restrict__ intervals, const float* __restrict__ bias_p,
    float* __restrict__ outU, float* __restrict__ outO,
    float* __restrict__ degs,
    int ncols, int n_vars, int nchunks) {
  int t = blockIdx.x * TPB + threadIdx.x;
  int two_n = 2 * n_vars;
  if (t < two_n) degs[t] = 1.0f;

  if (t < ncols) {
    float s = bias_p[0];
    for (int c = 0; c < nchunks; ++c) s += pu[(size_t)c * ncols + t];
    float vx = s, vy = s;
    if (t == 0) { vx = intervals[0] * s; vy = intervals[1] * s; }
    size_t off = (size_t)t * two_n;
    outU[off] = vx; outU[off + 1] = vy;
  } else if (t < 2 * ncols) {
    int j = t - ncols;
    float s = bias_p[0];
    for (int c = 0; c < nchunks; ++c) s += po[(size_t)c * ncols + j];
    float vx = s, vy = s;
    if (j == 0) { vx = intervals[0] * s; vy = intervals[1] * s; }
    size_t off = (size_t)j * two_n;
    outO[off] = vx; outO[off + 1] = vy;
  }
}

extern "C" void kernel_launch(void* const* d_in, const int* in_sizes, int n_in,
                              void* d_out, int out_size, void* d_ws, size_t ws_size,
                              hipStream_t stream) {
  const float* U         = (const float*)d_in[0];  // (K, n_vars+1)
  const float* O         = (const float*)d_in[1];  // (K, n_vars+1)
  const float* intervals = (const float*)d_in[4];  // (n_vars, 2)
  const float* pos       = (const float*)d_in[5];  // (K,)
  const float* neg       = (const float*)d_in[6];  // (K,)
  const float* bias      = (const float*)d_in[7];  // (1,)

  const int n_vars = in_sizes[4] / 2;
  const int K      = in_sizes[5];
  const int ncols  = n_vars + 1;

  // Partial-sum workspace: (nchunks, ncols) for each of under/over.
  int nchunks = 32;
  while (nchunks > 1 && (size_t)2 * nchunks * ncols * sizeof(float) > ws_size)
    nchunks >>= 1;
  float* pu = (float*)d_ws;
  float* po = pu + (size_t)nchunks * ncols;

  const int col_tiles = (ncols + TPB - 1) / TPB;
  const int rpc = (K + nchunks - 1) / nchunks;
  const int n_gemv_blocks = col_tiles * nchunks;

  const long long S = (long long)ncols * n_vars * 2;  // elements per tensor
  float* outU = (float*)d_out;
  float* outO = outU + S;
  float* degs = outU + 2 * S;

  const int two_n = 2 * n_vars;
  const bool pow2 = two_n > 0 && (two_n & (two_n - 1)) == 0;

  if (pow2 && S / 4 < (1LL << 31)) {
    int shift = __builtin_ctz((unsigned)two_n);
    int n4 = (int)(S / 4);
    int fill_blocks = (n4 + TPB - 1) / TPB;
    int grid = n_gemv_blocks + fill_blocks;
    fused_gemv_fill<<<grid, TPB, 0, stream>>>(
        U, O, pos, neg, intervals, pu, po, outU, outO,
        K, ncols, col_tiles, rpc, shift, two_n - 1, n4, n_gemv_blocks);
  } else {
    // Separate launches for the general case.
    fused_gemv_fill<<<n_gemv_blocks, TPB, 0, stream>>>(
        U, O, pos, neg, intervals, pu, po, outU, outO,
        K, ncols, col_tiles, rpc, 0, 0, 0, n_gemv_blocks);
    fill_scalar<<<4096, TPB, 0, stream>>>(intervals, outU, outO, n_vars, S);
  }

  int nB = (2 * ncols > two_n ? 2 * ncols : two_n);
  finish<<<(nB + TPB - 1) / TPB, TPB, 0, stream>>>(
      pu, po, intervals, bias, outU, outO, degs, ncols, n_vars, nchunks);
}